// Round 1
// baseline (516.005 us; speedup 1.0000x reference)
//
#include <hip/hip_runtime.h>
#include <math.h>

typedef short short8 __attribute__((ext_vector_type(8)));
typedef short short4v __attribute__((ext_vector_type(4)));
typedef float float4v __attribute__((ext_vector_type(4)));

// bf16 round-to-nearest-even from fp32, as raw bits in a short
__device__ __forceinline__ short f2bf(float f) {
    union { float f; unsigned u; } v; v.f = f;
    unsigned r = (v.u + 0x7FFFu + ((v.u >> 16) & 1u)) >> 16;
    return (short)r;
}

__device__ __forceinline__ void async16(const short* g, short* l) {
    __builtin_amdgcn_global_load_lds(
        (const __attribute__((address_space(1))) unsigned*)g,
        (__attribute__((address_space(3))) unsigned*)l, 16, 0, 0);
}

// ---------------- fp32 -> bf16 convert (weights) ----------------
__global__ void cvt_kernel(const float* __restrict__ src, short* __restrict__ dst, int n4) {
    int i = blockIdx.x * blockDim.x + threadIdx.x;
    if (i < n4) {
        float4v v = ((const float4v*)src)[i];
        short4v o;
        o[0] = f2bf(v[0]); o[1] = f2bf(v[1]); o[2] = f2bf(v[2]); o[3] = f2bf(v[3]);
        ((short4v*)dst)[i] = o;
    }
}

// ---------------- fused fp32->bf16 + sign-mask for queries/keys ----------------
__global__ __launch_bounds__(256) void cvtmask_kernel(
    const float* __restrict__ q, const float* __restrict__ k,
    short* __restrict__ qb, short* __restrict__ kb,
    float* __restrict__ qm, float* __restrict__ km) {
    int tid = threadIdx.x;
    int lane = tid & 63, wv = tid >> 6;
    int row = blockIdx.x * 4 + wv;
    const float* src; short* dst; float* msk; int r;
    if (row < 16384) { src = q; dst = qb; msk = qm; r = row; }
    else             { src = k; dst = kb; msk = km; r = row - 16384; }
    const float4v* p = (const float4v*)(src + (size_t)r * 512);
    float4v a = p[lane];
    float4v b = p[lane + 64];
    short4v o1, o2;
    o1[0] = f2bf(a[0]); o1[1] = f2bf(a[1]); o1[2] = f2bf(a[2]); o1[3] = f2bf(a[3]);
    o2[0] = f2bf(b[0]); o2[1] = f2bf(b[1]); o2[2] = f2bf(b[2]); o2[3] = f2bf(b[3]);
    short4v* d4 = (short4v*)(dst + (size_t)r * 512);
    d4[lane] = o1;
    d4[lane + 64] = o2;
    float s = fabsf(a[0]) + fabsf(a[1]) + fabsf(a[2]) + fabsf(a[3])
            + fabsf(b[0]) + fabsf(b[1]) + fabsf(b[2]) + fabsf(b[3]);
    #pragma unroll
    for (int off = 1; off < 64; off <<= 1) s += __shfl_xor(s, off, 64);
    if (lane == 0) msk[r] = (s > 0.f) ? 1.f : 0.f;
}

// ---------------- fused projection GEMM (m97 structure, BK=64) ----------------
__global__ __launch_bounds__(256) void proj_kernel(
    const short* __restrict__ Xq, const short* __restrict__ Xk,
    const short* __restrict__ Wqp, const short* __restrict__ Wkp, const short* __restrict__ Wvp,
    const float* __restrict__ bqp, const float* __restrict__ bkp, const float* __restrict__ bvp,
    short* __restrict__ Qo, short* __restrict__ Ko, short* __restrict__ Vo) {
    __shared__ short As[128 * 64];
    __shared__ short Bs[128 * 64];
    int z = blockIdx.z;
    const short* X    = (z == 0) ? Xq  : Xk;
    const short* W    = (z == 0) ? Wqp : (z == 1) ? Wkp : Wvp;
    const float* bias = (z == 0) ? bqp : (z == 1) ? bkp : bvp;
    short* out        = (z == 0) ? Qo  : (z == 1) ? Ko  : Vo;

    int tid = threadIdx.x;
    int lane = tid & 63, wv = tid >> 6;
    int col = lane & 15, quad = lane >> 4;
    int m0 = blockIdx.x * 128;
    int n0 = blockIdx.y * 128;
    int msub = (wv & 1) * 64, nsub = (wv >> 1) * 64;

    float4v acc[4][4];
    #pragma unroll
    for (int mt = 0; mt < 4; ++mt)
        #pragma unroll
        for (int nt = 0; nt < 4; ++nt) { acc[mt][nt][0]=0.f; acc[mt][nt][1]=0.f; acc[mt][nt][2]=0.f; acc[mt][nt][3]=0.f; }

    int rowS = tid >> 3;   // 0..31
    int seg  = tid & 7;    // 16B segment within a 128B row
    const short* gA = X + (size_t)(m0 + rowS) * 512 + seg * 8;
    const short* gB = W + (size_t)(n0 + rowS) * 512 + seg * 8;
    short* lA = As + (size_t)tid * 8;
    short* lB = Bs + (size_t)tid * 8;

    for (int k0 = 0; k0 < 512; k0 += 64) {
        __syncthreads();
        #pragma unroll
        for (int j = 0; j < 4; ++j) {
            async16(gA + (size_t)(j * 32) * 512 + k0, lA + j * 2048);
            async16(gB + (size_t)(j * 32) * 512 + k0, lB + j * 2048);
        }
        __syncthreads();
        #pragma unroll
        for (int ksub = 0; ksub < 2; ++ksub) {
            short8 a[4], b[4];
            #pragma unroll
            for (int mt = 0; mt < 4; ++mt)
                a[mt] = *(const short8*)(As + (msub + mt * 16 + col) * 64 + ksub * 32 + quad * 8);
            #pragma unroll
            for (int nt = 0; nt < 4; ++nt)
                b[nt] = *(const short8*)(Bs + (nsub + nt * 16 + col) * 64 + ksub * 32 + quad * 8);
            #pragma unroll
            for (int mt = 0; mt < 4; ++mt)
                #pragma unroll
                for (int nt = 0; nt < 4; ++nt)
                    acc[mt][nt] = __builtin_amdgcn_mfma_f32_16x16x32_bf16(a[mt], b[nt], acc[mt][nt], 0, 0, 0);
        }
    }

    #pragma unroll
    for (int nt = 0; nt < 4; ++nt) {
        float bv = bias[n0 + nsub + nt * 16 + col];
        #pragma unroll
        for (int mt = 0; mt < 4; ++mt) {
            #pragma unroll
            for (int r = 0; r < 4; ++r) {
                int m = m0 + msub + mt * 16 + quad * 4 + r;
                out[(size_t)m * 512 + n0 + nsub + nt * 16 + col] = f2bf(acc[mt][nt][r] + bv);
            }
        }
    }
}

// ---------------- fused attention ----------------
// grid: (bh=256, qt=8) so all 8 q-tiles of one (b,h) land on one XCD (linear%8).
// block 256 = 4 waves, 16 q-rows per wave. Scores computed TRANSPOSED:
// D[kk][q] via mfma(A=K-rows, B=Q-rows): lane holds q=col, kk = t*16+quad*4+r.
// Causal tile-skip: wave-uniform predication over STATIC-unrolled tile loops
// (dynamic trip count would runtime-index sc[] -> scratch spill).
// V^T preloaded ONCE into swizzled LDS (1 barrier total, conflict-free scatter).
// aw/out stores nontemporal: 256MB stream must not thrash the 4MB per-XCD L2
// that caches this XCD's K/V slices.
__global__ __launch_bounds__(256) void attn_kernel(
    const short* __restrict__ Q, const short* __restrict__ K, const short* __restrict__ V,
    const float* __restrict__ qmask, const float* __restrict__ kmask,
    const int* __restrict__ caus, float* __restrict__ out, float* __restrict__ aw) {
    // V^T: vt[d][ck], d=0..63, ck=0..511, row stride 520 shorts (=1040B, 16B-aligned).
    // Column XOR swizzle ck ^= ((d>>3)&7)<<3 on BOTH write and read:
    //   scatter writes (8 rows apart = bank-0 aligned) spread over 8 banks -> conflict-free;
    //   b128 reads stay 2-way (free); 8-short blocks stay contiguous (XOR on bits>=3).
    __shared__ short vt[64 * 520];
    __shared__ short wl[4 * 16 * 72];    // per-wave w chunk [q][kk], stride 72 (144B, 16B-aligned)

    int tid = threadIdx.x;
    int lane = tid & 63, wv = tid >> 6;
    int col = lane & 15, quad = lane >> 4;
    int bh = blockIdx.x, qt = blockIdx.y;
    int b = bh >> 3, h = bh & 7;
    int q0 = qt * 64 + wv * 16;
    size_t rowbase = (size_t)b * 512;
    bool causal = (*caus) != 0;
    // last score tile this wave must compute: tile t covers k in [16t,16t+15];
    // needed iff 16t <= q0+15  ->  t <= qt*4+wv  (wave-uniform)
    int lim = causal ? (qt * 4 + wv) : 31;
    // last PV chunk (64 k) needed by ANY wave of the block: c <= qt (block-uniform)
    int climit = causal ? qt : 7;

    // Q B-frags: lane n=col -> q-row q0+col, k = quad*8+j (two 32-chunks over dh=64)
    short8 bQ0, bQ1;
    {
        const short* qp = Q + (rowbase + q0 + col) * 512 + h * 64 + quad * 8;
        bQ0 = *(const short8*)(qp);
        bQ1 = *(const short8*)(qp + 32);
    }

    // scores (transposed): sc[t][r] = S[kk = t*16+quad*4+r][q = q0+col]
    float4v sc[32];
    const short* kp = K + (rowbase + col) * 512 + h * 64 + quad * 8;
    const float* kmp = kmask + b * 512;
    int qg = q0 + col;
    #pragma unroll
    for (int t = 0; t < 32; ++t) {
        if (t <= lim) {
            short8 aK0 = *(const short8*)(kp + (size_t)(t * 16) * 512);
            short8 aK1 = *(const short8*)(kp + (size_t)(t * 16) * 512 + 32);
            float4v s; s[0]=0.f; s[1]=0.f; s[2]=0.f; s[3]=0.f;
            s = __builtin_amdgcn_mfma_f32_16x16x32_bf16(aK0, bQ0, s, 0, 0, 0);
            s = __builtin_amdgcn_mfma_f32_16x16x32_bf16(aK1, bQ1, s, 0, 0, 0);
            int kb = t * 16 + quad * 4;
            float4v km4 = *(const float4v*)(kmp + kb);
            #pragma unroll
            for (int r = 0; r < 4; ++r) {
                float v = s[r] * 0.125f;  // 1/sqrt(64)
                bool masked = (km4[r] == 0.f) || (causal && (kb + r > qg));
                sc[t][r] = masked ? -INFINITY : v;
            }
        } else {
            sc[t][0]=0.f; sc[t][1]=0.f; sc[t][2]=0.f; sc[t][3]=0.f;
        }
    }

    // softmax over k: per lane all values share q=col; reduce across quads
    float mx = -INFINITY;
    #pragma unroll
    for (int t = 0; t < 32; ++t)
        if (t <= lim) {
            #pragma unroll
            for (int r = 0; r < 4; ++r) mx = fmaxf(mx, sc[t][r]);
        }
    mx = fmaxf(mx, __shfl_xor(mx, 16, 64));
    mx = fmaxf(mx, __shfl_xor(mx, 32, 64));
    float sm = 0.f;
    #pragma unroll
    for (int t = 0; t < 32; ++t)
        if (t <= lim) {
            #pragma unroll
            for (int r = 0; r < 4; ++r) {
                float s = sc[t][r];
                float e = (s == -INFINITY) ? 0.f : __expf(s - mx);
                sc[t][r] = e;
                sm += e;
            }
        }
    sm += __shfl_xor(sm, 16, 64);
    sm += __shfl_xor(sm, 32, 64);
    float qmv = qmask[b * 512 + qg];
    float inv = (sm > 0.f) ? (qmv / sm) : 0.f;  // nan_to_num + post-softmax query mask

    // attention weights [B][H][Lq][Lk]: lane holds 4 consecutive k -> nt dwordx4.
    // Skipped tiles are exact zeros (causal mask -> w=0).
    {
        float* awr = aw + ((size_t)b * 8 + h) * 512 * 512 + (size_t)qg * 512 + quad * 4;
        float4v z4; z4[0]=0.f; z4[1]=0.f; z4[2]=0.f; z4[3]=0.f;
        #pragma unroll
        for (int t = 0; t < 32; ++t) {
            if (t <= lim) {
                #pragma unroll
                for (int r = 0; r < 4; ++r) sc[t][r] *= inv;
                __builtin_nontemporal_store(sc[t], (float4v*)(awr + t * 16));
            } else {
                __builtin_nontemporal_store(z4, (float4v*)(awr + t * 16));
            }
        }
    }

    // one-shot V^T preload for needed chunks (stores above remain in flight)
    #pragma unroll
    for (int c = 0; c < 8; ++c) {
        if (c <= climit) {
            #pragma unroll
            for (int i = 0; i < 2; ++i) {
                int idx = i * 256 + tid;
                int kk = idx >> 3, sg = idx & 7;   // kk: k within chunk, sg: 8-d segment
                short8 v8 = *(const short8*)(V + (rowbase + c * 64 + kk) * 512 + h * 64 + sg * 8);
                int ck = (c * 64 + kk) ^ (sg << 3);   // swizzle key = d>>3 = sg
                #pragma unroll
                for (int j = 0; j < 8; ++j)
                    vt[(sg * 8 + j) * 520 + ck] = v8[j];
            }
        }
    }
    __syncthreads();   // the ONLY barrier in this kernel

    // PV: O[q][d] = sum_k w[q][k] * V[k][d]; wl is wave-private (no barriers needed:
    // DS ops from one wave are processed in order, write->read same addr is safe)
    float4v O[4];
    #pragma unroll
    for (int nt = 0; nt < 4; ++nt) { O[nt][0]=0.f; O[nt][1]=0.f; O[nt][2]=0.f; O[nt][3]=0.f; }
    short* wlw = wl + wv * (16 * 72);
    #pragma unroll
    for (int c = 0; c < 8; ++c) {
        if (c <= climit) {
            // stage this wave's w chunk as bf16 [q][kk]: lane writes 4 consecutive kk
            #pragma unroll
            for (int tl = 0; tl < 4; ++tl) {
                int t = c * 4 + tl;
                short4v w4;
                #pragma unroll
                for (int r = 0; r < 4; ++r) w4[r] = f2bf(sc[t][r]);
                *(short4v*)(wlw + col * 72 + tl * 16 + quad * 4) = w4;
            }
            #pragma unroll
            for (int sub = 0; sub < 2; ++sub) {
                short8 aW = *(const short8*)(wlw + col * 72 + sub * 32 + quad * 8);
                #pragma unroll
                for (int nt = 0; nt < 4; ++nt) {
                    int d = nt * 16 + col;
                    int cb = (c * 64 + sub * 32 + quad * 8) ^ (((d >> 3) & 7) << 3);
                    short8 bV = *(const short8*)(vt + d * 520 + cb);
                    O[nt] = __builtin_amdgcn_mfma_f32_16x16x32_bf16(aW, bV, O[nt], 0, 0, 0);
                }
            }
        }
    }
    // out[b][l][h*64+d]; D[q][d]: row=quad*4+r is q-offset, col is d
    #pragma unroll
    for (int nt = 0; nt < 4; ++nt) {
        #pragma unroll
        for (int r = 0; r < 4; ++r) {
            int qq = q0 + quad * 4 + r;
            __builtin_nontemporal_store(O[nt][r],
                out + (rowbase + qq) * 512 + h * 64 + nt * 16 + col);
        }
    }
}

extern "C" void kernel_launch(void* const* d_in, const int* in_sizes, int n_in,
                              void* d_out, int out_size, void* d_ws, size_t ws_size,
                              hipStream_t stream) {
    const float* queries = (const float*)d_in[0];
    const float* keys    = (const float*)d_in[1];
    const float* Wq      = (const float*)d_in[2];
    const float* bq      = (const float*)d_in[3];
    const float* Wk      = (const float*)d_in[4];
    const float* bk      = (const float*)d_in[5];
    const float* Wv      = (const float*)d_in[6];
    const float* bv      = (const float*)d_in[7];
    const int*   caus    = (const int*)d_in[8];

    const size_t NE = (size_t)16384 * 512;
    short* qbf = (short*)d_ws;
    short* kbf = qbf + NE;
    short* Qb  = kbf + NE;
    short* Kb  = Qb + NE;
    short* Vb  = Kb + NE;
    short* wqb = Vb + NE;
    short* wkb = wqb + 512 * 512;
    short* wvb = wkb + 512 * 512;
    float* qm  = (float*)(wvb + 512 * 512);
    float* km  = qm + 32 * 512;

    cvtmask_kernel<<<8192, 256, 0, stream>>>(queries, keys, qbf, kbf, qm, km);
    cvt_kernel<<<256, 256, 0, stream>>>(Wq, wqb, 65536);
    cvt_kernel<<<256, 256, 0, stream>>>(Wk, wkb, 65536);
    cvt_kernel<<<256, 256, 0, stream>>>(Wv, wvb, 65536);
    dim3 pg(128, 4, 3);
    proj_kernel<<<pg, 256, 0, stream>>>(qbf, kbf, wqb, wkb, wvb, bq, bk, bv, Qb, Kb, Vb);
    float* outp = (float*)d_out;
    float* awp  = outp + 8388608;
    dim3 ag(256, 8);
    attn_kernel<<<ag, 256, 0, stream>>>(Qb, Kb, Vb, qm, km, caus, outp, awp);
}

// Round 3
// 500.927 us; speedup vs baseline: 1.0301x; 1.0301x over previous
//
#include <hip/hip_runtime.h>
#include <math.h>

typedef short short8 __attribute__((ext_vector_type(8)));
typedef short short4v __attribute__((ext_vector_type(4)));
typedef float float4v __attribute__((ext_vector_type(4)));

// bf16 round-to-nearest-even from fp32, as raw bits in a short
__device__ __forceinline__ short f2bf(float f) {
    union { float f; unsigned u; } v; v.f = f;
    unsigned r = (v.u + 0x7FFFu + ((v.u >> 16) & 1u)) >> 16;
    return (short)r;
}

__device__ __forceinline__ void async16(const short* g, short* l) {
    __builtin_amdgcn_global_load_lds(
        (const __attribute__((address_space(1))) unsigned*)g,
        (__attribute__((address_space(3))) unsigned*)l, 16, 0, 0);
}

// ---------------- fp32 -> bf16 convert, all 3 weight matrices in one launch ----------------
__global__ __launch_bounds__(256) void cvt3_kernel(
    const float* __restrict__ w0, const float* __restrict__ w1, const float* __restrict__ w2,
    short* __restrict__ d0, short* __restrict__ d1, short* __restrict__ d2) {
    int i = blockIdx.x * blockDim.x + threadIdx.x;  // 0 .. 3*65536
    int sel = i >> 16;
    int j = i & 65535;
    const float* src = (sel == 0) ? w0 : (sel == 1) ? w1 : w2;
    short* dst       = (sel == 0) ? d0 : (sel == 1) ? d1 : d2;
    float4v v = ((const float4v*)src)[j];
    short4v o;
    o[0] = f2bf(v[0]); o[1] = f2bf(v[1]); o[2] = f2bf(v[2]); o[3] = f2bf(v[3]);
    ((short4v*)dst)[j] = o;
}

// ---------------- fused fp32->bf16 + sign-mask for queries/keys ----------------
__global__ __launch_bounds__(256) void cvtmask_kernel(
    const float* __restrict__ q, const float* __restrict__ k,
    short* __restrict__ qb, short* __restrict__ kb,
    float* __restrict__ qm, float* __restrict__ km) {
    int tid = threadIdx.x;
    int lane = tid & 63, wv = tid >> 6;
    int row = blockIdx.x * 4 + wv;
    const float* src; short* dst; float* msk; int r;
    if (row < 16384) { src = q; dst = qb; msk = qm; r = row; }
    else             { src = k; dst = kb; msk = km; r = row - 16384; }
    const float4v* p = (const float4v*)(src + (size_t)r * 512);
    float4v a = p[lane];
    float4v b = p[lane + 64];
    short4v o1, o2;
    o1[0] = f2bf(a[0]); o1[1] = f2bf(a[1]); o1[2] = f2bf(a[2]); o1[3] = f2bf(a[3]);
    o2[0] = f2bf(b[0]); o2[1] = f2bf(b[1]); o2[2] = f2bf(b[2]); o2[3] = f2bf(b[3]);
    short4v* d4 = (short4v*)(dst + (size_t)r * 512);
    d4[lane] = o1;
    d4[lane + 64] = o2;
    float s = fabsf(a[0]) + fabsf(a[1]) + fabsf(a[2]) + fabsf(a[3])
            + fabsf(b[0]) + fabsf(b[1]) + fabsf(b[2]) + fabsf(b[3]);
    #pragma unroll
    for (int off = 1; off < 64; off <<= 1) s += __shfl_xor(s, off, 64);
    if (lane == 0) msk[r] = (s > 0.f) ? 1.f : 0.f;
}

// ---------------- fused projection GEMM (m97 structure, BK=64) ----------------
__global__ __launch_bounds__(256) void proj_kernel(
    const short* __restrict__ Xq, const short* __restrict__ Xk,
    const short* __restrict__ Wqp, const short* __restrict__ Wkp, const short* __restrict__ Wvp,
    const float* __restrict__ bqp, const float* __restrict__ bkp, const float* __restrict__ bvp,
    short* __restrict__ Qo, short* __restrict__ Ko, short* __restrict__ Vo) {
    __shared__ short As[128 * 64];
    __shared__ short Bs[128 * 64];
    int z = blockIdx.z;
    const short* X    = (z == 0) ? Xq  : Xk;
    const short* W    = (z == 0) ? Wqp : (z == 1) ? Wkp : Wvp;
    const float* bias = (z == 0) ? bqp : (z == 1) ? bkp : bvp;
    short* out        = (z == 0) ? Qo  : (z == 1) ? Ko  : Vo;

    int tid = threadIdx.x;
    int lane = tid & 63, wv = tid >> 6;
    int col = lane & 15, quad = lane >> 4;
    int m0 = blockIdx.x * 128;
    int n0 = blockIdx.y * 128;
    int msub = (wv & 1) * 64, nsub = (wv >> 1) * 64;

    float4v acc[4][4];
    #pragma unroll
    for (int mt = 0; mt < 4; ++mt)
        #pragma unroll
        for (int nt = 0; nt < 4; ++nt) { acc[mt][nt][0]=0.f; acc[mt][nt][1]=0.f; acc[mt][nt][2]=0.f; acc[mt][nt][3]=0.f; }

    int rowS = tid >> 3;   // 0..31
    int seg  = tid & 7;    // 16B segment within a 128B row
    const short* gA = X + (size_t)(m0 + rowS) * 512 + seg * 8;
    const short* gB = W + (size_t)(n0 + rowS) * 512 + seg * 8;
    short* lA = As + (size_t)tid * 8;
    short* lB = Bs + (size_t)tid * 8;

    for (int k0 = 0; k0 < 512; k0 += 64) {
        __syncthreads();
        #pragma unroll
        for (int j = 0; j < 4; ++j) {
            async16(gA + (size_t)(j * 32) * 512 + k0, lA + j * 2048);
            async16(gB + (size_t)(j * 32) * 512 + k0, lB + j * 2048);
        }
        __syncthreads();
        #pragma unroll
        for (int ksub = 0; ksub < 2; ++ksub) {
            short8 a[4], b[4];
            #pragma unroll
            for (int mt = 0; mt < 4; ++mt)
                a[mt] = *(const short8*)(As + (msub + mt * 16 + col) * 64 + ksub * 32 + quad * 8);
            #pragma unroll
            for (int nt = 0; nt < 4; ++nt)
                b[nt] = *(const short8*)(Bs + (nsub + nt * 16 + col) * 64 + ksub * 32 + quad * 8);
            #pragma unroll
            for (int mt = 0; mt < 4; ++mt)
                #pragma unroll
                for (int nt = 0; nt < 4; ++nt)
                    acc[mt][nt] = __builtin_amdgcn_mfma_f32_16x16x32_bf16(a[mt], b[nt], acc[mt][nt], 0, 0, 0);
        }
    }

    #pragma unroll
    for (int nt = 0; nt < 4; ++nt) {
        float bv = bias[n0 + nsub + nt * 16 + col];
        #pragma unroll
        for (int mt = 0; mt < 4; ++mt) {
            #pragma unroll
            for (int r = 0; r < 4; ++r) {
                int m = m0 + msub + mt * 16 + quad * 4 + r;
                out[(size_t)m * 512 + n0 + nsub + nt * 16 + col] = f2bf(acc[mt][nt][r] + bv);
            }
        }
    }
}

// ---------------- fused attention, two-pass online softmax ----------------
// grid: (bh=256, qt=8); block 256 = 4 waves, 16 q-rows/wave. Scores TRANSPOSED:
// D[kk][q] via mfma(A=K-rows, B=Q-rows): lane holds q=col, kk = t*16+quad*4+r.
// Pass 1: stream tiles, maintain per-lane running (m,l) in log2 domain — no score
//   array retained -> VGPR peak drops vs score-retaining version -> more waves/SIMD.
// Pass 2: recompute tiles (K hits L1/L2), w = exp2(s*C - m)*inv final, store aw,
//   pack bf16, PV per 64-k chunk from a double-buffered 9KB V^T stage
//   (register-prefetched one chunk ahead; ONE barrier per chunk, block-uniform guard).
// Causal wave-uniform tile skip retained; nontemporal aw/out retained.
__global__ __launch_bounds__(256) void attn_kernel(
    const short* __restrict__ Q, const short* __restrict__ K, const short* __restrict__ V,
    const float* __restrict__ qmask, const float* __restrict__ kmask,
    const int* __restrict__ caus, float* __restrict__ out, float* __restrict__ aw) {
    // per-chunk V^T buffer: vtb[buf][d][lck], stride 72 shorts (=144B).
    // XOR swizzle lck = kk ^ (sg<<3) on write, cb = koff ^ ((d>>3&7)<<3) on read.
    __shared__ short vtb[2][64 * 72];
    __shared__ short wl[4 * 16 * 72];    // per-wave w chunk [q][kk]

    int tid = threadIdx.x;
    int lane = tid & 63, wv = tid >> 6;
    int col = lane & 15, quad = lane >> 4;
    int bh = blockIdx.x, qt = blockIdx.y;
    int b = bh >> 3, h = bh & 7;
    int q0 = qt * 64 + wv * 16;
    size_t rowbase = (size_t)b * 512;
    bool causal = (*caus) != 0;
    int lim = causal ? (qt * 4 + wv) : 31;   // wave-uniform last score tile
    int climit = causal ? qt : 7;            // block-uniform last PV chunk

    // Q B-frags: lane n=col -> q-row q0+col, k = quad*8+j
    short8 bQ0, bQ1;
    {
        const short* qp = Q + (rowbase + q0 + col) * 512 + h * 64 + quad * 8;
        bQ0 = *(const short8*)(qp);
        bQ1 = *(const short8*)(qp + 32);
    }

    const short* kp = K + (rowbase + col) * 512 + h * 64 + quad * 8;
    const float* kmp = kmask + b * 512;
    int qg = q0 + col;
    const float C = 0.125f * 1.44269504089f;  // (1/sqrt(64)) * log2(e): exp -> exp2 domain

    // ---- pass 1: online (m, l) ----
    float m = -INFINITY, l = 0.f;
    #pragma unroll
    for (int t = 0; t < 32; ++t) {
        if (t <= lim) {
            short8 aK0 = *(const short8*)(kp + (size_t)(t * 16) * 512);
            short8 aK1 = *(const short8*)(kp + (size_t)(t * 16) * 512 + 32);
            float4v s; s[0]=0.f; s[1]=0.f; s[2]=0.f; s[3]=0.f;
            s = __builtin_amdgcn_mfma_f32_16x16x32_bf16(aK0, bQ0, s, 0, 0, 0);
            s = __builtin_amdgcn_mfma_f32_16x16x32_bf16(aK1, bQ1, s, 0, 0, 0);
            int kb = t * 16 + quad * 4;
            float4v km4 = *(const float4v*)(kmp + kb);
            float e0, e1, e2, e3, tmax;
            e0 = ((km4[0] != 0.f) && (!causal || (kb + 0 <= qg))) ? s[0] * C : -INFINITY;
            e1 = ((km4[1] != 0.f) && (!causal || (kb + 1 <= qg))) ? s[1] * C : -INFINITY;
            e2 = ((km4[2] != 0.f) && (!causal || (kb + 2 <= qg))) ? s[2] * C : -INFINITY;
            e3 = ((km4[3] != 0.f) && (!causal || (kb + 3 <= qg))) ? s[3] * C : -INFINITY;
            tmax = fmaxf(fmaxf(e0, e1), fmaxf(e2, e3));
            float nm = fmaxf(m, tmax);
            float f = (m == -INFINITY) ? 0.f : exp2f(m - nm);
            float ls = 0.f;
            ls += (e0 == -INFINITY) ? 0.f : exp2f(e0 - nm);
            ls += (e1 == -INFINITY) ? 0.f : exp2f(e1 - nm);
            ls += (e2 == -INFINITY) ? 0.f : exp2f(e2 - nm);
            ls += (e3 == -INFINITY) ? 0.f : exp2f(e3 - nm);
            l = l * f + ls;
            m = nm;
        }
    }
    // combine across the 4 quads (lanes sharing q=col)
    #pragma unroll
    for (int off = 16; off <= 32; off <<= 1) {
        float mo = __shfl_xor(m, off, 64);
        float lo = __shfl_xor(l, off, 64);
        float M = fmaxf(m, mo);
        float fa = (m  == -INFINITY) ? 0.f : exp2f(m - M);
        float fb = (mo == -INFINITY) ? 0.f : exp2f(mo - M);
        l = l * fa + lo * fb;
        m = M;
    }
    float qmv = qmask[b * 512 + qg];
    float inv = (l > 0.f) ? (qmv / l) : 0.f;  // nan_to_num + post-softmax query mask

    // ---- pass 2: recompute, store aw, PV with double-buffered V^T ----
    int kk0 = tid >> 3, sgv = tid & 7;
    const short* vp = V + rowbase * 512 + h * 64 + sgv * 8;
    int lck0 = kk0 ^ (sgv << 3);
    int lck1 = (kk0 + 32) ^ (sgv << 3);
    // prefetch chunk 0 (always needed: climit >= 0)
    short8 pva = *(const short8*)(vp + (size_t)(kk0) * 512);
    short8 pvb = *(const short8*)(vp + (size_t)(kk0 + 32) * 512);

    float4v O[4];
    #pragma unroll
    for (int nt = 0; nt < 4; ++nt) { O[nt][0]=0.f; O[nt][1]=0.f; O[nt][2]=0.f; O[nt][3]=0.f; }
    short* wlw = wl + wv * (16 * 72);
    float* awr = aw + ((size_t)b * 8 + h) * 512 * 512 + (size_t)qg * 512 + quad * 4;
    float4v z4; z4[0]=0.f; z4[1]=0.f; z4[2]=0.f; z4[3]=0.f;

    #pragma unroll
    for (int c = 0; c < 8; ++c) {
        if (c <= climit) {   // block-uniform -> barrier-safe
            short* vb = &vtb[c & 1][0];
            // write prefetched chunk c; double buffering makes one barrier per
            // chunk race-free (next chunk's writes go to the other buffer)
            #pragma unroll
            for (int j = 0; j < 8; ++j) vb[(sgv * 8 + j) * 72 + lck0] = pva[j];
            #pragma unroll
            for (int j = 0; j < 8; ++j) vb[(sgv * 8 + j) * 72 + lck1] = pvb[j];
            __syncthreads();
            // prefetch chunk c+1
            if (c + 1 <= climit) {
                pva = *(const short8*)(vp + (size_t)((c + 1) * 64 + kk0) * 512);
                pvb = *(const short8*)(vp + (size_t)((c + 1) * 64 + kk0 + 32) * 512);
            }
            // recompute 4 tiles, final w, aw store, bf16 pack into wl
            #pragma unroll
            for (int tl = 0; tl < 4; ++tl) {
                int t = c * 4 + tl;
                short4v w4;
                if (t <= lim) {
                    short8 aK0 = *(const short8*)(kp + (size_t)(t * 16) * 512);
                    short8 aK1 = *(const short8*)(kp + (size_t)(t * 16) * 512 + 32);
                    float4v s; s[0]=0.f; s[1]=0.f; s[2]=0.f; s[3]=0.f;
                    s = __builtin_amdgcn_mfma_f32_16x16x32_bf16(aK0, bQ0, s, 0, 0, 0);
                    s = __builtin_amdgcn_mfma_f32_16x16x32_bf16(aK1, bQ1, s, 0, 0, 0);
                    int kb = t * 16 + quad * 4;
                    float4v km4 = *(const float4v*)(kmp + kb);
                    float4v w;
                    #pragma unroll
                    for (int r = 0; r < 4; ++r) {
                        bool ok = (km4[r] != 0.f) && (!causal || (kb + r <= qg)) && (inv > 0.f);
                        float wvv = ok ? exp2f(s[r] * C - m) * inv : 0.f;
                        w[r] = wvv;
                        w4[r] = f2bf(wvv);
                    }
                    __builtin_nontemporal_store(w, (float4v*)(awr + t * 16));
                } else {
                    w4[0]=0; w4[1]=0; w4[2]=0; w4[3]=0;
                    __builtin_nontemporal_store(z4, (float4v*)(awr + t * 16));
                }
                *(short4v*)(wlw + col * 72 + tl * 16 + quad * 4) = w4;
            }
            // PV on this chunk
            #pragma unroll
            for (int sub = 0; sub < 2; ++sub) {
                short8 aW = *(const short8*)(wlw + col * 72 + sub * 32 + quad * 8);
                #pragma unroll
                for (int nt = 0; nt < 4; ++nt) {
                    int d = nt * 16 + col;
                    int cb = (sub * 32 + quad * 8) ^ (((d >> 3) & 7) << 3);
                    short8 bV = *(const short8*)(vb + d * 72 + cb);
                    O[nt] = __builtin_amdgcn_mfma_f32_16x16x32_bf16(aW, bV, O[nt], 0, 0, 0);
                }
            }
        } else {
            // beyond causal horizon: aw rows are exact zeros
            #pragma unroll
            for (int tl = 0; tl < 4; ++tl)
                __builtin_nontemporal_store(z4, (float4v*)(awr + (c * 4 + tl) * 16));
        }
    }

    // out[b][l][h*64+d]; D[q][d]: row=quad*4+r is q-offset, col is d
    #pragma unroll
    for (int nt = 0; nt < 4; ++nt) {
        #pragma unroll
        for (int r = 0; r < 4; ++r) {
            int qq = q0 + quad * 4 + r;
            __builtin_nontemporal_store(O[nt][r],
                out + (rowbase + qq) * 512 + h * 64 + nt * 16 + col);
        }
    }
}

extern "C" void kernel_launch(void* const* d_in, const int* in_sizes, int n_in,
                              void* d_out, int out_size, void* d_ws, size_t ws_size,
                              hipStream_t stream) {
    const float* queries = (const float*)d_in[0];
    const float* keys    = (const float*)d_in[1];
    const float* Wq      = (const float*)d_in[2];
    const float* bq      = (const float*)d_in[3];
    const float* Wk      = (const float*)d_in[4];
    const float* bk      = (const float*)d_in[5];
    const float* Wv      = (const float*)d_in[6];
    const float* bv      = (const float*)d_in[7];
    const int*   caus    = (const int*)d_in[8];

    const size_t NE = (size_t)16384 * 512;
    short* qbf = (short*)d_ws;
    short* kbf = qbf + NE;
    short* Qb  = kbf + NE;
    short* Kb  = Qb + NE;
    short* Vb  = Kb + NE;
    short* wqb = Vb + NE;
    short* wkb = wqb + 512 * 512;
    short* wvb = wkb + 512 * 512;
    float* qm  = (float*)(wvb + 512 * 512);
    float* km  = qm + 32 * 512;

    cvtmask_kernel<<<8192, 256, 0, stream>>>(queries, keys, qbf, kbf, qm, km);
    cvt3_kernel<<<768, 256, 0, stream>>>(Wq, Wk, Wv, wqb, wkb, wvb);
    dim3 pg(128, 4, 3);
    proj_kernel<<<pg, 256, 0, stream>>>(qbf, kbf, wqb, wkb, wvb, bq, bk, bv, Qb, Kb, Vb);
    float* outp = (float*)d_out;
    float* awp  = outp + 8388608;
    dim3 ag(256, 8);
    attn_kernel<<<ag, 256, 0, stream>>>(Qb, Kb, Vb, qm, km, caus, outp, awp);
}